// Round 2
// baseline (163.029 us; speedup 1.0000x reference)
//
#include <hip/hip_runtime.h>

#define B_ 4
#define S_ 512
#define T_ 512
#define D_ 256
#define NSRC (B_ * S_)        // 2048 source rows
#define K2F 2.8853900817779268f   // 2*log2(e): exp2(x*K2F) = e^(2x)

typedef __attribute__((ext_vector_type(8))) short short8;   // 8 bf16 (4 VGPRs)
typedef __attribute__((ext_vector_type(4))) float f32x4;

__device__ __forceinline__ unsigned short f2bf(float f) {
    union { float f; unsigned u; } v; v.f = f;
    unsigned r = v.u + 0x7FFF + ((v.u >> 16) & 1);   // round-to-nearest-even
    return (unsigned short)(r >> 16);
}

// ---------------------------------------------------------------------------
// Cast A = [source rows ; target rows] fp32 -> bf16. 1M elems, float4 per thread.
// ---------------------------------------------------------------------------
__global__ __launch_bounds__(256) void cast_a_kernel(
    const float* __restrict__ src, const float* __restrict__ tgt,
    unsigned short* __restrict__ abf)
{
    int i4 = blockIdx.x * 256 + threadIdx.x;          // 0..262143 float4s
    const int half = NSRC * D_ / 4;                   // 131072
    const float4* in = (i4 < half) ? (const float4*)src : (const float4*)tgt;
    int j = (i4 < half) ? i4 : i4 - half;
    float4 v = in[j];
    ushort4 o;
    o.x = f2bf(v.x); o.y = f2bf(v.y); o.z = f2bf(v.z); o.w = f2bf(v.w);
    *(ushort4*)&abf[i4 * 4] = o;
}

// ---------------------------------------------------------------------------
// WT[e][j][k] = W_e[k][j], cast to bf16. One block per (e, j) output row.
// ---------------------------------------------------------------------------
__global__ __launch_bounds__(256) void cast_wt_kernel(
    const float* __restrict__ Wsrc, const float* __restrict__ Wtgt,
    unsigned short* __restrict__ wtb)
{
    int e = blockIdx.x >> 8;        // 0 src, 1 tgt
    int j = blockIdx.x & 255;       // output row = column of W
    const float* W = e ? Wtgt : Wsrc;
    int k = threadIdx.x;
    wtb[(e * 256 + j) * D_ + k] = f2bf(W[k * D_ + j]);
}

// ---------------------------------------------------------------------------
// MFMA GEMM + exp: ya/yc[r][j] = exp2((A@W + b) * K2F).
// 2048 waves; wave = 16 rows x 32 cols (2 c-frags). Direct global->frag loads:
//   A-frag: A[m=lane&15][k=quad*8+j] -> b128 from row-major A_bf16
//   B-frag: B[k][n=lane&15]          -> b128 from WT rows (WT[j][k]=W[k][j])
//   D: col=lane&15, row=quad*4+reg   (m89/m91-verified layouts)
// ---------------------------------------------------------------------------
__global__ __launch_bounds__(256) void lin_gemm_kernel(
    const unsigned short* __restrict__ abf, const unsigned short* __restrict__ wtb,
    const float* __restrict__ bsrc, const float* __restrict__ btgt,
    float* __restrict__ ya, float* __restrict__ yc)
{
    int wid  = blockIdx.x * 4 + (threadIdx.x >> 6);   // 0..2047
    int lane = threadIdx.x & 63;
    int rg = wid >> 3;                                // 0..255 row-group
    int cg = wid & 7;                                 // 0..7 col-group (32 cols)
    int e  = rg >> 7;                                 // 0 src, 1 tgt
    int r0 = rg * 16;                                 // row in abf (0..4095)
    int n = lane & 15, quad = lane >> 4;

    const float* bias = e ? btgt : bsrc;
    float* out = e ? yc : ya;
    int orow0 = r0 - e * NSRC;

    int ct0 = cg * 2, ct1 = cg * 2 + 1;
    f32x4 acc0 = {0.f, 0.f, 0.f, 0.f};
    f32x4 acc1 = {0.f, 0.f, 0.f, 0.f};

    const unsigned short* aP  = &abf[(r0 + n) * D_ + quad * 8];
    const unsigned short* b0P = &wtb[(e * 256 + ct0 * 16 + n) * D_ + quad * 8];
    const unsigned short* b1P = &wtb[(e * 256 + ct1 * 16 + n) * D_ + quad * 8];

    #pragma unroll
    for (int ks = 0; ks < 8; ks++) {
        short8 a  = *(const short8*)&aP[ks * 32];
        short8 b0 = *(const short8*)&b0P[ks * 32];
        short8 b1 = *(const short8*)&b1P[ks * 32];
        acc0 = __builtin_amdgcn_mfma_f32_16x16x32_bf16(a, b0, acc0, 0, 0, 0);
        acc1 = __builtin_amdgcn_mfma_f32_16x16x32_bf16(a, b1, acc1, 0, 0, 0);
    }

    float b0v = bias[ct0 * 16 + n];
    float b1v = bias[ct1 * 16 + n];
    #pragma unroll
    for (int i = 0; i < 4; i++) {
        int row = orow0 + quad * 4 + i;
        out[row * D_ + ct0 * 16 + n] = __builtin_amdgcn_exp2f((acc0[i] + b0v) * K2F);
        out[row * D_ + ct1 * 16 + n] = __builtin_amdgcn_exp2f((acc1[i] + b1v) * K2F);
    }
}

// ---------------------------------------------------------------------------
// genP: out[b,t,s] += (dc==0 ? C0 : 0) - 2 * sum_{d in chunk} w_d/(1+ya*yc)
// Split-D: grid (8,8,16), z = b*4+dc. 256 thr, tile 64t x 64s, thread 4t x 4s.
// Staging: lane l = row, wave-uniform k4 -> LDS write banks (4k4+4i+l)%32 = 2-way (free).
// Inner reads: av b128 (2-way free), cv b128 (4 broadcast addrs), wl broadcast.
// ---------------------------------------------------------------------------
#define STR 68
__global__ __launch_bounds__(256) void genp_kernel(
    const float* __restrict__ ya, const float* __restrict__ yc,
    const float* __restrict__ Wres, const float* __restrict__ bres,
    float* __restrict__ out)
{
    __shared__ float la[64 * STR];
    __shared__ float lc[64 * STR];
    __shared__ float wl[64];
    __shared__ float c0s;

    const int tid = threadIdx.x;
    const int w = tid >> 6, l = tid & 63;
    const int s0 = blockIdx.x * 64;
    const int t0 = blockIdx.y * 64;
    const int b  = blockIdx.z >> 2;
    const int dc = blockIdx.z & 3;
    const int d0 = dc * 64;

    const float* arow = &ya[(b * S_ + s0 + l) * D_ + d0];
    const float* crow = &yc[(b * T_ + t0 + l) * D_ + d0];
    #pragma unroll
    for (int it = 0; it < 4; it++) {
        int k4 = w * 16 + it * 4;
        float4 va = *(const float4*)&arow[k4];
        la[(k4 + 0) * STR + l] = va.x;
        la[(k4 + 1) * STR + l] = va.y;
        la[(k4 + 2) * STR + l] = va.z;
        la[(k4 + 3) * STR + l] = va.w;
        float4 vc = *(const float4*)&crow[k4];
        lc[(k4 + 0) * STR + l] = vc.x;
        lc[(k4 + 1) * STR + l] = vc.y;
        lc[(k4 + 2) * STR + l] = vc.z;
        lc[(k4 + 3) * STR + l] = vc.w;
    }
    if (tid < 64) wl[tid] = Wres[d0 + tid];
    if (dc == 0 && w == 0) {
        float s = Wres[l] + Wres[64 + l] + Wres[128 + l] + Wres[192 + l];
        #pragma unroll
        for (int off = 32; off > 0; off >>= 1) s += __shfl_down(s, off, 64);
        if (l == 0) c0s = s + bres[0];
    }
    __syncthreads();

    const int m = tid & 15;     // s-group
    const int g = tid >> 4;     // t-group 0..15
    float acc[4][4];
    #pragma unroll
    for (int i = 0; i < 4; i++)
        #pragma unroll
        for (int j = 0; j < 4; j++) acc[i][j] = 0.f;

    #pragma unroll 4
    for (int k = 0; k < 64; k++) {
        float4 av = *(const float4*)&la[k * STR + 4 * m];
        float4 cv = *(const float4*)&lc[k * STR + 4 * g];
        float wv = wl[k];
        float a0 = av.x, a1 = av.y, a2 = av.z, a3 = av.w;
        float c0 = cv.x, c1 = cv.y, c2 = cv.z, c3 = cv.w;
        float r;
        r = __builtin_amdgcn_rcpf(fmaf(c0, a0, 1.f)); acc[0][0] = fmaf(wv, r, acc[0][0]);
        r = __builtin_amdgcn_rcpf(fmaf(c0, a1, 1.f)); acc[0][1] = fmaf(wv, r, acc[0][1]);
        r = __builtin_amdgcn_rcpf(fmaf(c0, a2, 1.f)); acc[0][2] = fmaf(wv, r, acc[0][2]);
        r = __builtin_amdgcn_rcpf(fmaf(c0, a3, 1.f)); acc[0][3] = fmaf(wv, r, acc[0][3]);
        r = __builtin_amdgcn_rcpf(fmaf(c1, a0, 1.f)); acc[1][0] = fmaf(wv, r, acc[1][0]);
        r = __builtin_amdgcn_rcpf(fmaf(c1, a1, 1.f)); acc[1][1] = fmaf(wv, r, acc[1][1]);
        r = __builtin_amdgcn_rcpf(fmaf(c1, a2, 1.f)); acc[1][2] = fmaf(wv, r, acc[1][2]);
        r = __builtin_amdgcn_rcpf(fmaf(c1, a3, 1.f)); acc[1][3] = fmaf(wv, r, acc[1][3]);
        r = __builtin_amdgcn_rcpf(fmaf(c2, a0, 1.f)); acc[2][0] = fmaf(wv, r, acc[2][0]);
        r = __builtin_amdgcn_rcpf(fmaf(c2, a1, 1.f)); acc[2][1] = fmaf(wv, r, acc[2][1]);
        r = __builtin_amdgcn_rcpf(fmaf(c2, a2, 1.f)); acc[2][2] = fmaf(wv, r, acc[2][2]);
        r = __builtin_amdgcn_rcpf(fmaf(c2, a3, 1.f)); acc[2][3] = fmaf(wv, r, acc[2][3]);
        r = __builtin_amdgcn_rcpf(fmaf(c3, a0, 1.f)); acc[3][0] = fmaf(wv, r, acc[3][0]);
        r = __builtin_amdgcn_rcpf(fmaf(c3, a1, 1.f)); acc[3][1] = fmaf(wv, r, acc[3][1]);
        r = __builtin_amdgcn_rcpf(fmaf(c3, a2, 1.f)); acc[3][2] = fmaf(wv, r, acc[3][2]);
        r = __builtin_amdgcn_rcpf(fmaf(c3, a3, 1.f)); acc[3][3] = fmaf(wv, r, acc[3][3]);
    }

    const float c0v = (dc == 0) ? c0s : 0.f;
    #pragma unroll
    for (int i = 0; i < 4; i++) {
        int t = t0 + 4 * g + i;
        float* o = &out[(b * T_ + t) * S_ + s0 + 4 * m];
        #pragma unroll
        for (int j = 0; j < 4; j++) {
            __hip_atomic_fetch_add(&o[j], c0v - 2.f * acc[i][j],
                                   __ATOMIC_RELAXED, __HIP_MEMORY_SCOPE_AGENT);
        }
    }
}

// ---------------------------------------------------------------------------
// prob = softmax(target @ W_prob + b_prob), 2 classes. One wave per row.
// ---------------------------------------------------------------------------
__global__ __launch_bounds__(256) void prob_kernel(
    const float* __restrict__ tgt, const float* __restrict__ Wp,
    const float* __restrict__ bp, float* __restrict__ out)
{
    const int row  = blockIdx.x * 4 + (threadIdx.x >> 6);
    const int lane = threadIdx.x & 63;
    float p0 = 0.f, p1 = 0.f;
    #pragma unroll
    for (int i = 0; i < 4; i++) {
        int d = lane + i * 64;
        float v = tgt[row * D_ + d];
        float2 w = *(const float2*)&Wp[d * 2];
        p0 = fmaf(v, w.x, p0);
        p1 = fmaf(v, w.y, p1);
    }
    #pragma unroll
    for (int off = 32; off > 0; off >>= 1) {
        p0 += __shfl_down(p0, off, 64);
        p1 += __shfl_down(p1, off, 64);
    }
    if (lane == 0) {
        const float L2E = 1.4426950408889634f;
        float l0 = p0 + bp[0], l1 = p1 + bp[1];
        float e10 = __builtin_amdgcn_exp2f((l1 - l0) * L2E);
        float e01 = __builtin_amdgcn_exp2f((l0 - l1) * L2E);
        out[B_ * T_ * S_ + row * 2 + 0] = __builtin_amdgcn_rcpf(1.f + e10);
        out[B_ * T_ * S_ + row * 2 + 1] = __builtin_amdgcn_rcpf(1.f + e01);
    }
}

extern "C" void kernel_launch(void* const* d_in, const int* in_sizes, int n_in,
                              void* d_out, int out_size, void* d_ws, size_t ws_size,
                              hipStream_t stream) {
    const float* source = (const float*)d_in[0];
    const float* target = (const float*)d_in[1];
    const float* W_src  = (const float*)d_in[2];
    const float* b_src  = (const float*)d_in[3];
    const float* W_tgt  = (const float*)d_in[4];
    const float* b_tgt  = (const float*)d_in[5];
    const float* W_res  = (const float*)d_in[6];
    const float* b_res  = (const float*)d_in[7];
    const float* W_prob = (const float*)d_in[8];
    const float* b_prob = (const float*)d_in[9];
    float* out = (float*)d_out;

    // workspace layout
    float* ya = (float*)d_ws;                          // 2048*256 f32 = 2 MB
    float* yc = ya + NSRC * D_;                        // 2 MB
    unsigned short* abf = (unsigned short*)(yc + NSRC * D_);   // 4096*256 bf16 = 2 MB
    unsigned short* wtb = abf + 2 * NSRC * D_;                  // 2*256*256 bf16 = 256 KB

    // zero genP region (atomic accumulation target; poison is 0xAA)
    hipMemsetAsync(out, 0, (size_t)(B_ * T_ * S_) * sizeof(float), stream);

    cast_a_kernel<<<1024, 256, 0, stream>>>(source, target, abf);
    cast_wt_kernel<<<512, 256, 0, stream>>>(W_src, W_tgt, wtb);
    lin_gemm_kernel<<<512, 256, 0, stream>>>(abf, wtb, b_src, b_tgt, ya, yc);
    genp_kernel<<<dim3(8, 8, 16), 256, 0, stream>>>(ya, yc, W_res, b_res, out);
    prob_kernel<<<B_ * T_ / 4, 256, 0, stream>>>(target, W_prob, b_prob, out);
}

// Round 3
// 128.284 us; speedup vs baseline: 1.2708x; 1.2708x over previous
//
#include <hip/hip_runtime.h>

#define B_ 4
#define S_ 512
#define T_ 512
#define D_ 256
#define NSRC (B_ * S_)            // 2048 source rows
#define K2F 2.8853900817779268f   // 2*log2(e): exp2(x*K2F) = e^(2x)

typedef __attribute__((ext_vector_type(8))) short short8;   // 8 bf16
typedef __attribute__((ext_vector_type(4))) float f32x4;

__device__ __forceinline__ unsigned short f2bf(float f) {
    union { float f; unsigned u; } v; v.f = f;
    unsigned r = v.u + 0x7FFF + ((v.u >> 16) & 1);   // RNE
    return (unsigned short)(r >> 16);
}

// ---------------------------------------------------------------------------
// K1: prep. blocks 0..1023: cast [src;tgt] -> abf bf16 (float4/thread).
//     blocks 1024..1055: W -> WT bf16 via LDS 64x64 tile transpose.
//     blocks 1056..1567: prob = softmax(target @ W_prob + b_prob).
// ---------------------------------------------------------------------------
__global__ __launch_bounds__(256) void prep_kernel(
    const float* __restrict__ src, const float* __restrict__ tgt,
    const float* __restrict__ Wsrc, const float* __restrict__ Wtgt,
    const float* __restrict__ Wp, const float* __restrict__ bp,
    unsigned short* __restrict__ abf, unsigned short* __restrict__ wtb,
    float* __restrict__ out)
{
    __shared__ float tl[64 * 65];
    const int blk = blockIdx.x, tid = threadIdx.x;

    if (blk < 1024) {
        int i4 = blk * 256 + tid;                    // 0..262143 float4s
        const int half = NSRC * D_ / 4;              // 131072
        const float4* in = (i4 < half) ? (const float4*)src : (const float4*)tgt;
        int j = (i4 < half) ? i4 : i4 - half;
        float4 v = in[j];
        ushort4 o;
        o.x = f2bf(v.x); o.y = f2bf(v.y); o.z = f2bf(v.z); o.w = f2bf(v.w);
        *(ushort4*)&abf[i4 * 4] = o;
    } else if (blk < 1056) {
        int wb = blk - 1024;
        int e = wb >> 4, ti = wb & 15, tr = ti >> 2, tc = ti & 3;
        int r0 = tr * 64, c0 = tc * 64;
        const float* W = e ? Wtgt : Wsrc;
        #pragma unroll
        for (int it = 0; it < 4; it++) {
            int rr = (tid >> 4) + it * 16;
            int cc = (tid & 15) * 4;
            float4 v = *(const float4*)&W[(r0 + rr) * D_ + c0 + cc];
            tl[(cc + 0) * 65 + rr] = v.x;
            tl[(cc + 1) * 65 + rr] = v.y;
            tl[(cc + 2) * 65 + rr] = v.z;
            tl[(cc + 3) * 65 + rr] = v.w;
        }
        __syncthreads();
        #pragma unroll
        for (int it = 0; it < 2; it++) {
            int jj = (tid >> 3) + it * 32;           // 0..63 (WT row offset)
            int kk = (tid & 7) * 8;                  // 0..56 (WT col offset)
            ushort4 lo, hi;
            lo.x = f2bf(tl[jj * 65 + kk + 0]); lo.y = f2bf(tl[jj * 65 + kk + 1]);
            lo.z = f2bf(tl[jj * 65 + kk + 2]); lo.w = f2bf(tl[jj * 65 + kk + 3]);
            hi.x = f2bf(tl[jj * 65 + kk + 4]); hi.y = f2bf(tl[jj * 65 + kk + 5]);
            hi.z = f2bf(tl[jj * 65 + kk + 6]); hi.w = f2bf(tl[jj * 65 + kk + 7]);
            int idx = (e * 256 + c0 + jj) * D_ + r0 + kk;   // wtb[e][j][k] = W[k][j]
            *(ushort4*)&wtb[idx] = lo;
            *(ushort4*)&wtb[idx + 4] = hi;
        }
    } else {
        int row  = (blk - 1056) * 4 + (tid >> 6);
        int lane = tid & 63;
        float p0 = 0.f, p1 = 0.f;
        #pragma unroll
        for (int i = 0; i < 4; i++) {
            int d = lane + i * 64;
            float v = tgt[row * D_ + d];
            float2 w = *(const float2*)&Wp[d * 2];
            p0 = fmaf(v, w.x, p0);
            p1 = fmaf(v, w.y, p1);
        }
        #pragma unroll
        for (int off = 32; off > 0; off >>= 1) {
            p0 += __shfl_down(p0, off, 64);
            p1 += __shfl_down(p1, off, 64);
        }
        if (lane == 0) {
            const float L2E = 1.4426950408889634f;
            float l0 = p0 + bp[0], l1 = p1 + bp[1];
            float e10 = __builtin_amdgcn_exp2f((l1 - l0) * L2E);
            float e01 = __builtin_amdgcn_exp2f((l0 - l1) * L2E);
            out[B_ * T_ * S_ + row * 2 + 0] = __builtin_amdgcn_rcpf(1.f + e10);
            out[B_ * T_ * S_ + row * 2 + 1] = __builtin_amdgcn_rcpf(1.f + e01);
        }
    }
}

// ---------------------------------------------------------------------------
// K2: mega. Block = (bs,bt,b): 32 s-rows x 32 t-rows tile, full D.
// Phase A: MFMA lin for own rows; wave w: mat=w>>1 (s/t), n0 in (w&1)*8..+8;
//   A-frag rows kept in regs (2 rg x 8 ks); B-frags streamed from wtb.
//   exp2 epilogue -> lexp[mat][d][row] (stride 33, conflict-free phase-B reads).
// Phase B: genP[t][s] = C0 - 2*sum_d w_d / (1 + ys*yt); 2t x 2s per thread.
// ---------------------------------------------------------------------------
__global__ __launch_bounds__(256) void mega_kernel(
    const unsigned short* __restrict__ abf, const unsigned short* __restrict__ wtb,
    const float* __restrict__ bsrc, const float* __restrict__ btgt,
    const float* __restrict__ Wres, const float* __restrict__ bres,
    float* __restrict__ out)
{
    __shared__ float ls[D_ * 33];   // [d][s], 33 KB
    __shared__ float lt[D_ * 33];   // [d][t]
    __shared__ float wl[D_];
    __shared__ float c0s;

    const int tid = threadIdx.x;
    const int lane = tid & 63, w = tid >> 6;
    const int s0 = blockIdx.x * 32;
    const int t0 = blockIdx.y * 32;
    const int b  = blockIdx.z;

    wl[tid] = Wres[tid];
    if (w == 0) {
        float s = Wres[lane] + Wres[lane + 64] + Wres[lane + 128] + Wres[lane + 192];
        #pragma unroll
        for (int off = 32; off > 0; off >>= 1) s += __shfl_xor(s, off, 64);
        if (lane == 0) c0s = s + bres[0];
    }

    // ---- Phase A ----
    const int mat = w >> 1;                     // 0 = s-rows, 1 = t-rows
    const int n = lane & 15, quad = lane >> 4;
    const float* bias = mat ? btgt : bsrc;
    float* lx = mat ? lt : ls;
    const int R = mat ? (NSRC + b * T_ + t0) : (b * S_ + s0);

    short8 af[2][8];
    #pragma unroll
    for (int rg = 0; rg < 2; rg++)
        #pragma unroll
        for (int ks = 0; ks < 8; ks++)
            af[rg][ks] = *(const short8*)&abf[(R + rg * 16 + n) * D_ + ks * 32 + quad * 8];

    const int n0beg = (w & 1) * 8;
    #pragma unroll
    for (int n0 = n0beg; n0 < n0beg + 8; n0++) {
        const unsigned short* bp = &wtb[(mat * 256 + n0 * 16 + n) * D_ + quad * 8];
        short8 bf[8];
        #pragma unroll
        for (int ks = 0; ks < 8; ks++) bf[ks] = *(const short8*)&bp[ks * 32];
        f32x4 acc0 = {0.f, 0.f, 0.f, 0.f};
        f32x4 acc1 = {0.f, 0.f, 0.f, 0.f};
        #pragma unroll
        for (int ks = 0; ks < 8; ks++) {
            acc0 = __builtin_amdgcn_mfma_f32_16x16x32_bf16(af[0][ks], bf[ks], acc0, 0, 0, 0);
            acc1 = __builtin_amdgcn_mfma_f32_16x16x32_bf16(af[1][ks], bf[ks], acc1, 0, 0, 0);
        }
        const int dcol = n0 * 16 + n;
        const float bv = bias[dcol];
        #pragma unroll
        for (int i = 0; i < 4; i++) {
            lx[dcol * 33 + quad * 4 + i]      = __builtin_amdgcn_exp2f((acc0[i] + bv) * K2F);
            lx[dcol * 33 + 16 + quad * 4 + i] = __builtin_amdgcn_exp2f((acc1[i] + bv) * K2F);
        }
    }
    __syncthreads();

    // ---- Phase B ----
    const int m = tid & 15;    // s pair: 2m, 2m+1
    const int g = tid >> 4;    // t pair: 2g, 2g+1
    float a00 = 0.f, a01 = 0.f, a10 = 0.f, a11 = 0.f;

    #pragma unroll 8
    for (int k = 0; k < D_; k++) {
        float2 av = *(const float2*)&ls[k * 33 + 2 * m];
        float2 cv = *(const float2*)&lt[k * 33 + 2 * g];
        float wv = wl[k];
        float r;
        r = __builtin_amdgcn_rcpf(fmaf(cv.x, av.x, 1.f)); a00 = fmaf(wv, r, a00);
        r = __builtin_amdgcn_rcpf(fmaf(cv.x, av.y, 1.f)); a01 = fmaf(wv, r, a01);
        r = __builtin_amdgcn_rcpf(fmaf(cv.y, av.x, 1.f)); a10 = fmaf(wv, r, a10);
        r = __builtin_amdgcn_rcpf(fmaf(cv.y, av.y, 1.f)); a11 = fmaf(wv, r, a11);
    }

    const float C0 = c0s;
    float2 o0, o1;
    o0.x = C0 - 2.f * a00; o0.y = C0 - 2.f * a01;
    o1.x = C0 - 2.f * a10; o1.y = C0 - 2.f * a11;
    *(float2*)&out[(b * T_ + t0 + 2 * g + 0) * S_ + s0 + 2 * m] = o0;
    *(float2*)&out[(b * T_ + t0 + 2 * g + 1) * S_ + s0 + 2 * m] = o1;
}

extern "C" void kernel_launch(void* const* d_in, const int* in_sizes, int n_in,
                              void* d_out, int out_size, void* d_ws, size_t ws_size,
                              hipStream_t stream) {
    const float* source = (const float*)d_in[0];
    const float* target = (const float*)d_in[1];
    const float* W_src  = (const float*)d_in[2];
    const float* b_src  = (const float*)d_in[3];
    const float* W_tgt  = (const float*)d_in[4];
    const float* b_tgt  = (const float*)d_in[5];
    const float* W_res  = (const float*)d_in[6];
    const float* b_res  = (const float*)d_in[7];
    const float* W_prob = (const float*)d_in[8];
    const float* b_prob = (const float*)d_in[9];
    float* out = (float*)d_out;

    unsigned short* abf = (unsigned short*)d_ws;        // 4096*256 bf16 = 2 MB
    unsigned short* wtb = abf + 2 * NSRC * D_;          // 2*256*256 bf16 = 256 KB

    prep_kernel<<<1568, 256, 0, stream>>>(source, target, W_src, W_tgt,
                                          W_prob, b_prob, abf, wtb, out);
    mega_kernel<<<dim3(16, 16, 4), 256, 0, stream>>>(abf, wtb, b_src, b_tgt,
                                                     W_res, b_res, out);
}

// Round 4
// 126.537 us; speedup vs baseline: 1.2884x; 1.0138x over previous
//
#include <hip/hip_runtime.h>

#define B_ 4
#define S_ 512
#define T_ 512
#define D_ 256
#define NSRC (B_ * S_)            // 2048 source rows
#define K2F 2.8853900817779268f   // 2*log2(e): exp2(x*K2F) = e^(2x)

typedef __attribute__((ext_vector_type(8))) short short8;   // 8 bf16
typedef __attribute__((ext_vector_type(4))) float f32x4;

__device__ __forceinline__ unsigned short f2bf(float f) {
    union { float f; unsigned u; } v; v.f = f;
    unsigned r = v.u + 0x7FFF + ((v.u >> 16) & 1);   // RNE
    return (unsigned short)(r >> 16);
}

// ---------------------------------------------------------------------------
// K1: prep (validated R3). blocks 0..1023: cast [src;tgt] -> abf bf16.
//     blocks 1024..1055: W -> WT bf16 via LDS 64x64 tile transpose.
//     blocks 1056..1567: prob = softmax(target @ W_prob + b_prob).
// ---------------------------------------------------------------------------
__global__ __launch_bounds__(256) void prep_kernel(
    const float* __restrict__ src, const float* __restrict__ tgt,
    const float* __restrict__ Wsrc, const float* __restrict__ Wtgt,
    const float* __restrict__ Wp, const float* __restrict__ bp,
    unsigned short* __restrict__ abf, unsigned short* __restrict__ wtb,
    float* __restrict__ out)
{
    __shared__ float tl[64 * 65];
    const int blk = blockIdx.x, tid = threadIdx.x;

    if (blk < 1024) {
        int i4 = blk * 256 + tid;
        const int half = NSRC * D_ / 4;
        const float4* in = (i4 < half) ? (const float4*)src : (const float4*)tgt;
        int j = (i4 < half) ? i4 : i4 - half;
        float4 v = in[j];
        ushort4 o;
        o.x = f2bf(v.x); o.y = f2bf(v.y); o.z = f2bf(v.z); o.w = f2bf(v.w);
        *(ushort4*)&abf[i4 * 4] = o;
    } else if (blk < 1056) {
        int wb = blk - 1024;
        int e = wb >> 4, ti = wb & 15, tr = ti >> 2, tc = ti & 3;
        int r0 = tr * 64, c0 = tc * 64;
        const float* W = e ? Wtgt : Wsrc;
        #pragma unroll
        for (int it = 0; it < 4; it++) {
            int rr = (tid >> 4) + it * 16;
            int cc = (tid & 15) * 4;
            float4 v = *(const float4*)&W[(r0 + rr) * D_ + c0 + cc];
            tl[(cc + 0) * 65 + rr] = v.x;
            tl[(cc + 1) * 65 + rr] = v.y;
            tl[(cc + 2) * 65 + rr] = v.z;
            tl[(cc + 3) * 65 + rr] = v.w;
        }
        __syncthreads();
        #pragma unroll
        for (int it = 0; it < 2; it++) {
            int jj = (tid >> 3) + it * 32;
            int kk = (tid & 7) * 8;
            ushort4 lo, hi;
            lo.x = f2bf(tl[jj * 65 + kk + 0]); lo.y = f2bf(tl[jj * 65 + kk + 1]);
            lo.z = f2bf(tl[jj * 65 + kk + 2]); lo.w = f2bf(tl[jj * 65 + kk + 3]);
            hi.x = f2bf(tl[jj * 65 + kk + 4]); hi.y = f2bf(tl[jj * 65 + kk + 5]);
            hi.z = f2bf(tl[jj * 65 + kk + 6]); hi.w = f2bf(tl[jj * 65 + kk + 7]);
            int idx = (e * 256 + c0 + jj) * D_ + r0 + kk;
            *(ushort4*)&wtb[idx] = lo;
            *(ushort4*)&wtb[idx + 4] = hi;
        }
    } else {
        int row  = (blk - 1056) * 4 + (tid >> 6);
        int lane = tid & 63;
        float p0 = 0.f, p1 = 0.f;
        #pragma unroll
        for (int i = 0; i < 4; i++) {
            int d = lane + i * 64;
            float v = tgt[row * D_ + d];
            float2 w = *(const float2*)&Wp[d * 2];
            p0 = fmaf(v, w.x, p0);
            p1 = fmaf(v, w.y, p1);
        }
        #pragma unroll
        for (int off = 32; off > 0; off >>= 1) {
            p0 += __shfl_down(p0, off, 64);
            p1 += __shfl_down(p1, off, 64);
        }
        if (lane == 0) {
            const float L2E = 1.4426950408889634f;
            float l0 = p0 + bp[0], l1 = p1 + bp[1];
            float e10 = __builtin_amdgcn_exp2f((l1 - l0) * L2E);
            float e01 = __builtin_amdgcn_exp2f((l0 - l1) * L2E);
            out[B_ * T_ * S_ + row * 2 + 0] = __builtin_amdgcn_rcpf(1.f + e10);
            out[B_ * T_ * S_ + row * 2 + 1] = __builtin_amdgcn_rcpf(1.f + e01);
        }
    }
}

// ---------------------------------------------------------------------------
// K2: mega v2. Block = 64s x 64t tile, grid (8,8,4) = 256 = 1 block/CU.
// D chunked by 64. Per chunk:
//   Phase A: wave w (mat=w>>1: 0=s,1=t; half=w&1): A-frags for all 64 rows of
//     its mat resident (af[4][8], 128 VGPR); streams 2 colgroups of W-frags;
//     MFMA full-K; exp2 epilogue -> lx[d][row] stride 68 via b128 writes
//     (D-layout rows quad*4+i are contiguous).
//   Phase B: 4x4 thread tile (m: 4 s, g: 4 t); 64 k-steps of 16 rcp + 32 fma.
// genP = C0 - 2 * sum_d w_d / (1 + ys*yt),  C0 = sum w + b_res.
// ---------------------------------------------------------------------------
__global__ __launch_bounds__(256, 1) void mega_kernel(
    const unsigned short* __restrict__ abf, const unsigned short* __restrict__ wtb,
    const float* __restrict__ bsrc, const float* __restrict__ btgt,
    const float* __restrict__ Wres, const float* __restrict__ bres,
    float* __restrict__ out)
{
    __shared__ float ls[64 * 68];   // [d-in-chunk][s row], 17.4 KB
    __shared__ float lt[64 * 68];   // [d-in-chunk][t row]
    __shared__ float wl[D_];
    __shared__ float c0s;

    const int tid = threadIdx.x;
    const int lane = tid & 63, w = tid >> 6;
    const int s0 = blockIdx.x * 64;
    const int t0 = blockIdx.y * 64;
    const int b  = blockIdx.z;

    wl[tid] = Wres[tid];
    if (w == 0) {
        float s = Wres[lane] + Wres[lane + 64] + Wres[lane + 128] + Wres[lane + 192];
        #pragma unroll
        for (int off = 32; off > 0; off >>= 1) s += __shfl_xor(s, off, 64);
        if (lane == 0) c0s = s + bres[0];
    }

    // phase-A wave mapping
    const int mat  = w >> 1;           // 0 = s-rows, 1 = t-rows
    const int half = w & 1;            // which 2 colgroups per chunk
    const int n = lane & 15, quad = lane >> 4;
    const float* bias = mat ? btgt : bsrc;
    float* lx = mat ? lt : ls;
    const int R = mat ? (NSRC + b * T_ + t0) : (b * S_ + s0);

    // A-frags resident: 4 rowgroups x 8 ks (covers this mat's 64 rows, full K)
    short8 af[4][8];
    #pragma unroll
    for (int rg = 0; rg < 4; rg++)
        #pragma unroll
        for (int ks = 0; ks < 8; ks++)
            af[rg][ks] = *(const short8*)&abf[(R + rg * 16 + n) * D_ + ks * 32 + quad * 8];

    // phase-B thread mapping
    const int m = tid & 15;    // s = s0 + 4m..4m+3
    const int g = tid >> 4;    // t = t0 + 4g..4g+3
    float acc[4][4];
    #pragma unroll
    for (int i = 0; i < 4; i++)
        #pragma unroll
        for (int j = 0; j < 4; j++) acc[i][j] = 0.f;

    for (int c = 0; c < 4; c++) {
        // ---- Phase A: lin+exp for d-chunk c ----
        #pragma unroll
        for (int cgi = 0; cgi < 2; cgi++) {
            const int cg = half * 2 + cgi;         // colgroup within chunk 0..3
            const int gcol = c * 4 + cg;           // global colgroup 0..15
            const unsigned short* bptr = &wtb[(mat * 256 + gcol * 16 + n) * D_ + quad * 8];
            short8 bf[8];
            #pragma unroll
            for (int ks = 0; ks < 8; ks++) bf[ks] = *(const short8*)&bptr[ks * 32];
            const int dloc = cg * 16 + n;          // 0..63 within chunk
            const float bv = bias[gcol * 16 + n];
            #pragma unroll
            for (int rg = 0; rg < 4; rg++) {
                f32x4 a4 = {0.f, 0.f, 0.f, 0.f};
                #pragma unroll
                for (int ks = 0; ks < 8; ks++)
                    a4 = __builtin_amdgcn_mfma_f32_16x16x32_bf16(af[rg][ks], bf[ks], a4, 0, 0, 0);
                float4 o;
                o.x = __builtin_amdgcn_exp2f((a4[0] + bv) * K2F);
                o.y = __builtin_amdgcn_exp2f((a4[1] + bv) * K2F);
                o.z = __builtin_amdgcn_exp2f((a4[2] + bv) * K2F);
                o.w = __builtin_amdgcn_exp2f((a4[3] + bv) * K2F);
                *(float4*)&lx[dloc * 68 + rg * 16 + quad * 4] = o;
            }
        }
        __syncthreads();

        // ---- Phase B: 64 k-steps ----
        const float* wp = &wl[c * 64];
        #pragma unroll 8
        for (int k = 0; k < 64; k++) {
            float4 av = *(const float4*)&ls[k * 68 + 4 * m];
            float4 cv = *(const float4*)&lt[k * 68 + 4 * g];
            float wv = wp[k];
            float a0 = av.x, a1 = av.y, a2 = av.z, a3 = av.w;
            float c0 = cv.x, c1 = cv.y, c2 = cv.z, c3 = cv.w;
            float r;
            r = __builtin_amdgcn_rcpf(fmaf(c0, a0, 1.f)); acc[0][0] = fmaf(wv, r, acc[0][0]);
            r = __builtin_amdgcn_rcpf(fmaf(c0, a1, 1.f)); acc[0][1] = fmaf(wv, r, acc[0][1]);
            r = __builtin_amdgcn_rcpf(fmaf(c0, a2, 1.f)); acc[0][2] = fmaf(wv, r, acc[0][2]);
            r = __builtin_amdgcn_rcpf(fmaf(c0, a3, 1.f)); acc[0][3] = fmaf(wv, r, acc[0][3]);
            r = __builtin_amdgcn_rcpf(fmaf(c1, a0, 1.f)); acc[1][0] = fmaf(wv, r, acc[1][0]);
            r = __builtin_amdgcn_rcpf(fmaf(c1, a1, 1.f)); acc[1][1] = fmaf(wv, r, acc[1][1]);
            r = __builtin_amdgcn_rcpf(fmaf(c1, a2, 1.f)); acc[1][2] = fmaf(wv, r, acc[1][2]);
            r = __builtin_amdgcn_rcpf(fmaf(c1, a3, 1.f)); acc[1][3] = fmaf(wv, r, acc[1][3]);
            r = __builtin_amdgcn_rcpf(fmaf(c2, a0, 1.f)); acc[2][0] = fmaf(wv, r, acc[2][0]);
            r = __builtin_amdgcn_rcpf(fmaf(c2, a1, 1.f)); acc[2][1] = fmaf(wv, r, acc[2][1]);
            r = __builtin_amdgcn_rcpf(fmaf(c2, a2, 1.f)); acc[2][2] = fmaf(wv, r, acc[2][2]);
            r = __builtin_amdgcn_rcpf(fmaf(c2, a3, 1.f)); acc[2][3] = fmaf(wv, r, acc[2][3]);
            r = __builtin_amdgcn_rcpf(fmaf(c3, a0, 1.f)); acc[3][0] = fmaf(wv, r, acc[3][0]);
            r = __builtin_amdgcn_rcpf(fmaf(c3, a1, 1.f)); acc[3][1] = fmaf(wv, r, acc[3][1]);
            r = __builtin_amdgcn_rcpf(fmaf(c3, a2, 1.f)); acc[3][2] = fmaf(wv, r, acc[3][2]);
            r = __builtin_amdgcn_rcpf(fmaf(c3, a3, 1.f)); acc[3][3] = fmaf(wv, r, acc[3][3]);
        }
        __syncthreads();
    }

    const float C0 = c0s;
    #pragma unroll
    for (int i = 0; i < 4; i++) {
        float4 o;
        o.x = C0 - 2.f * acc[i][0];
        o.y = C0 - 2.f * acc[i][1];
        o.z = C0 - 2.f * acc[i][2];
        o.w = C0 - 2.f * acc[i][3];
        *(float4*)&out[(b * T_ + t0 + 4 * g + i) * S_ + s0 + 4 * m] = o;
    }
}

extern "C" void kernel_launch(void* const* d_in, const int* in_sizes, int n_in,
                              void* d_out, int out_size, void* d_ws, size_t ws_size,
                              hipStream_t stream) {
    const float* source = (const float*)d_in[0];
    const float* target = (const float*)d_in[1];
    const float* W_src  = (const float*)d_in[2];
    const float* b_src  = (const float*)d_in[3];
    const float* W_tgt  = (const float*)d_in[4];
    const float* b_tgt  = (const float*)d_in[5];
    const float* W_res  = (const float*)d_in[6];
    const float* b_res  = (const float*)d_in[7];
    const float* W_prob = (const float*)d_in[8];
    const float* b_prob = (const float*)d_in[9];
    float* out = (float*)d_out;

    unsigned short* abf = (unsigned short*)d_ws;        // 4096*256 bf16 = 2 MB
    unsigned short* wtb = abf + 2 * NSRC * D_;          // 2*256*256 bf16 = 256 KB

    prep_kernel<<<1568, 256, 0, stream>>>(source, target, W_src, W_tgt,
                                          W_prob, b_prob, abf, wtb, out);
    mega_kernel<<<dim3(8, 8, 4), 256, 0, stream>>>(abf, wtb, b_src, b_tgt,
                                                   W_res, b_res, out);
}